// Round 5
// baseline (114.512 us; speedup 1.0000x reference)
//
#include <hip/hip_runtime.h>
#include <hip/hip_bf16.h>

#define BT     16
#define C_IN   32
#define C_OUT  32
#define NRAND  16
#define NNODES 32768   // 32*32*32

typedef __attribute__((ext_vector_type(8))) short bf16x8;   // 8 bf16 = 4 VGPRs
typedef __attribute__((ext_vector_type(4))) float f32x4;

__device__ inline unsigned short f2bf(float f) {
    __hip_bfloat16 h = __float2bfloat16(f);
    return __builtin_bit_cast(unsigned short, h);
}

// ---------------------------------------------------------------------------
// x (b,c,m) fp32 -> xT2[bg][m][b2][c] bf16  (bg = b>>1, b2 = b&1).
// One node's pair-block = 128 B contiguous (2 batches x 32 c) = 1 cache line.
// Wave writes 4 nodes x 128 B fully contiguous.
// ---------------------------------------------------------------------------
__global__ __launch_bounds__(256) void build_xt_pair(
    const float* __restrict__ x, unsigned short* __restrict__ xT2) {
    __shared__ float tile[2][C_IN][65];       // 2-way LDS read alias = free
    const int bg    = blockIdx.y;             // 0..7 batch pair
    const int mbase = blockIdx.x * 64;
    const int tid   = threadIdx.x;

    #pragma unroll
    for (int i = 0; i < 4; ++i) {             // 1024 float4 reads, coalesced on m
        int lin = tid + i * 256;              // 0..1023
        int mg  = lin & 15;                   // x4 nodes
        int c   = (lin >> 4) & 31;
        int b2  = lin >> 9;
        float4 v = *reinterpret_cast<const float4*>(
            &x[((size_t)(bg * 2 + b2) * C_IN + c) * NNODES + mbase + mg * 4]);
        tile[b2][c][mg * 4 + 0] = v.x;
        tile[b2][c][mg * 4 + 1] = v.y;
        tile[b2][c][mg * 4 + 2] = v.z;
        tile[b2][c][mg * 4 + 3] = v.w;
    }
    __syncthreads();
    #pragma unroll
    for (int i = 0; i < 4; ++i) {             // 1024 ushort4 writes, contiguous
        int lin = tid + i * 256;
        int cg  = lin & 7;                    // x4 channels
        int b2  = (lin >> 3) & 1;
        int m0  = lin >> 4;                   // 0..63
        ushort4 u;
        u.x = f2bf(tile[b2][cg * 4 + 0][m0]);
        u.y = f2bf(tile[b2][cg * 4 + 1][m0]);
        u.z = f2bf(tile[b2][cg * 4 + 2][m0]);
        u.w = f2bf(tile[b2][cg * 4 + 3][m0]);
        *reinterpret_cast<ushort4*>(
            &xT2[(((size_t)bg * NNODES + mbase + m0) << 6) + b2 * 32 + cg * 4]) = u;
    }
}

// ---------------------------------------------------------------------------
// W (o,c,r) fp32 -> Wp bf16 in MFMA A-frag order (unchanged from R1):
//   Wp[(((h*16 + r)*4 + g)*16 + row)*8 + e] = W[o=h*16+row][c=g*8+e][r]
// ---------------------------------------------------------------------------
__global__ __launch_bounds__(256) void build_w_bf16(
    const float* __restrict__ w, unsigned short* __restrict__ Wp) {
    int i = blockIdx.x * 256 + threadIdx.x;   // 16384
    int e   = i & 7;
    int row = (i >> 3) & 15;
    int g   = (i >> 7) & 3;
    int r   = (i >> 9) & 15;
    int h   = i >> 13;
    int o = h * 16 + row;
    int c = g * 8 + e;
    Wp[i] = f2bf(w[((size_t)o * C_IN + c) * NRAND + r]);
}

// ---------------------------------------------------------------------------
// Main MFMA kernel. GEMM N-dim = 16 cols = (8 n x 2 b): per B-frag gather,
// the wave reads 8 random FULL 128 B lines (was 16 random 64 B half-lines).
// Block = 4 waves; wave tile = 32 o x (8 n x 2 b), 4 tiles; K = 512.
// XCD pins a batch-PAIR: per-XCD gather working set = 4 MiB (one L2).
// ---------------------------------------------------------------------------
__global__ __launch_bounds__(256) void mixer_mfma(
    const unsigned short* __restrict__ xT2,
    const unsigned short* __restrict__ Wp,
    const float* __restrict__ bias,
    const int*   __restrict__ idx,
    float*       __restrict__ out) {
    __shared__ unsigned short wlds[2 * NRAND * 4 * 16 * 8];   // 32 KiB

    const int bid   = blockIdx.x;             // 0..2047
    const int bg    = bid & 7;                // batch pair == XCD
    const int chunk = bid >> 3;               // 0..255 (128-node chunks)

    const int wave  = threadIdx.x >> 6;
    const int lane  = threadIdx.x & 63;
    const int col   = lane & 15;              // GEMM col = (nsub, b2)
    const int g     = lane >> 4;              // k-chunk: c = g*8..g*8+7
    const int b2    = col & 1;
    const int nsub  = col >> 1;               // 0..7
    const int nbase = chunk * 128 + wave * 32;

    const unsigned short* xg = xT2 + (((size_t)bg * NNODES) << 6);
    const int loff = b2 * 32 + g * 8;         // ushort offset in 128 B node block

    // ---- prologue: tile-0 idx + LDS fill + half-0 gathers ----
    const int4* ip0 = reinterpret_cast<const int4*>(idx) + (size_t)(nbase + nsub) * 4;
    int4 ipA0 = ip0[0], ipA1 = ip0[1], ipA2 = ip0[2], ipA3 = ip0[3];

    {
        const uint4* src = reinterpret_cast<const uint4*>(Wp);
        uint4*       dst = reinterpret_cast<uint4*>(wlds);
        #pragma unroll
        for (int i = 0; i < 8; ++i)
            dst[threadIdx.x + i * 256] = src[threadIdx.x + i * 256];
    }

    #define GATHER4(d0, d1, d2, d3, iv)                                             \
        d0 = *reinterpret_cast<const bf16x8*>(xg + (((size_t)(iv).x) << 6) + loff); \
        d1 = *reinterpret_cast<const bf16x8*>(xg + (((size_t)(iv).y) << 6) + loff); \
        d2 = *reinterpret_cast<const bf16x8*>(xg + (((size_t)(iv).z) << 6) + loff); \
        d3 = *reinterpret_cast<const bf16x8*>(xg + (((size_t)(iv).w) << 6) + loff)

    bf16x8 bufA[8];
    GATHER4(bufA[0], bufA[1], bufA[2], bufA[3], ipA0);
    GATHER4(bufA[4], bufA[5], bufA[6], bufA[7], ipA1);

    __syncthreads();

    const bf16x8* wfrag = reinterpret_cast<const bf16x8*>(wlds);
    const float4  bv0   = reinterpret_cast<const float4*>(bias)[g];
    const float4  bv1   = reinterpret_cast<const float4*>(bias)[g + 4];

    #pragma unroll 1
    for (int t = 0; t < 4; ++t) {
        // (a) prefetch next tile's idx rows
        int4 ipB0, ipB1, ipB2, ipB3;
        if (t < 3) {
            const int4* ipn = reinterpret_cast<const int4*>(idx)
                              + (size_t)(nbase + (t + 1) * 8 + nsub) * 4;
            ipB0 = ipn[0]; ipB1 = ipn[1]; ipB2 = ipn[2]; ipB3 = ipn[3];
        }

        // (b) half-1 gathers for current tile (r = 8..15)
        bf16x8 bufB[8];
        GATHER4(bufB[0], bufB[1], bufB[2], bufB[3], ipA2);
        GATHER4(bufB[4], bufB[5], bufB[6], bufB[7], ipA3);

        f32x4 c0 = {bv0.x, bv0.y, bv0.z, bv0.w};
        f32x4 c1 = {bv1.x, bv1.y, bv1.z, bv1.w};

        // (c) MFMA half-0 on bufA — bufB/ipB in flight underneath
        #pragma unroll
        for (int r = 0; r < 8; ++r) {
            c0 = __builtin_amdgcn_mfma_f32_16x16x32_bf16(
                     wfrag[(r * 4 + g) * 16 + (lane & 15)], bufA[r], c0, 0, 0, 0);
            c1 = __builtin_amdgcn_mfma_f32_16x16x32_bf16(
                     wfrag[((NRAND + r) * 4 + g) * 16 + (lane & 15)], bufA[r], c1, 0, 0, 0);
        }

        // (d) next tile's half-0 gathers into bufA
        if (t < 3) {
            GATHER4(bufA[0], bufA[1], bufA[2], bufA[3], ipB0);
            GATHER4(bufA[4], bufA[5], bufA[6], bufA[7], ipB1);
        }

        // (e) MFMA half-1 on bufB
        #pragma unroll
        for (int r = 8; r < 16; ++r) {
            c0 = __builtin_amdgcn_mfma_f32_16x16x32_bf16(
                     wfrag[(r * 4 + g) * 16 + (lane & 15)], bufB[r - 8], c0, 0, 0, 0);
            c1 = __builtin_amdgcn_mfma_f32_16x16x32_bf16(
                     wfrag[((NRAND + r) * 4 + g) * 16 + (lane & 15)], bufB[r - 8], c1, 0, 0, 0);
        }

        // (f) store: D col = lane&15 -> (nsub,b2), D row = g*4+jr -> o
        float* ob = out + (((size_t)(bg * 2 + b2) * C_OUT) << 15)
                        + nbase + t * 8 + nsub;
        #pragma unroll
        for (int jr = 0; jr < 4; ++jr) {
            __builtin_nontemporal_store(c0[jr], ob + (((size_t)(g * 4 + jr)) << 15));
            __builtin_nontemporal_store(c1[jr], ob + (((size_t)(g * 4 + jr + 16)) << 15));
        }

        ipA0 = ipB0; ipA1 = ipB1; ipA2 = ipB2; ipA3 = ipB3;
    }
    #undef GATHER4
}

// ---------------------------------------------------------------------------
// fp32 fallback (ws too small) — round-0 kernel, known-correct.
// ---------------------------------------------------------------------------
__global__ __launch_bounds__(256) void mixer_fallback(
    const float* __restrict__ xsrc, const float* __restrict__ wsrc,
    const float* __restrict__ bias, const int* __restrict__ idx,
    float* __restrict__ out) {
    const int b = blockIdx.y;
    const int n = blockIdx.x * 256 + threadIdx.x;
    float acc[C_OUT];
    #pragma unroll
    for (int o = 0; o < C_OUT; ++o) acc[o] = bias[o];
    #pragma unroll 1
    for (int r = 0; r < NRAND; ++r) {
        const int m = idx[(size_t)n * NRAND + r];
        #pragma unroll
        for (int c = 0; c < C_IN; ++c) {
            const float xs = xsrc[((size_t)b * C_IN + c) * NNODES + m];
            #pragma unroll
            for (int o = 0; o < C_OUT; ++o)
                acc[o] += wsrc[((size_t)o * C_IN + c) * NRAND + r] * xs;
        }
    }
    #pragma unroll
    for (int o = 0; o < C_OUT; ++o)
        out[((size_t)b * C_OUT + o) * NNODES + n] = acc[o];
}

// ---------------------------------------------------------------------------
extern "C" void kernel_launch(void* const* d_in, const int* in_sizes, int n_in,
                              void* d_out, int out_size, void* d_ws, size_t ws_size,
                              hipStream_t stream) {
    const float* x    = (const float*)d_in[0];
    const float* w    = (const float*)d_in[1];
    const float* bias = (const float*)d_in[2];
    const int*   idx  = (const int*)d_in[3];
    float*       out  = (float*)d_out;

    const size_t xT_bytes = (size_t)BT * NNODES * C_IN * sizeof(unsigned short); // 32 MiB
    const size_t wp_bytes = (size_t)2 * NRAND * 4 * 16 * 8 * sizeof(unsigned short); // 32 KiB

    if (ws_size >= xT_bytes + wp_bytes) {
        unsigned short* xT2 = (unsigned short*)d_ws;
        unsigned short* Wp  = (unsigned short*)((char*)d_ws + xT_bytes);

        dim3 tg(NNODES / 64, BT / 2);
        build_xt_pair<<<tg, 256, 0, stream>>>(x, xT2);
        build_w_bf16<<<(2 * NRAND * 4 * 16 * 8) / 256, 256, 0, stream>>>(w, Wp);

        mixer_mfma<<<BT / 2 * (NNODES / 128), 256, 0, stream>>>(xT2, Wp, bias, idx, out);
    } else {
        dim3 g(NNODES / 256, BT);
        mixer_fallback<<<g, 256, 0, stream>>>(x, w, bias, idx, out);
    }
}

// Round 6
// 73.918 us; speedup vs baseline: 1.5492x; 1.5492x over previous
//
#include <hip/hip_runtime.h>
#include <hip/hip_bf16.h>

#define BT     16
#define C_IN   32
#define C_OUT  32
#define NRAND  16
#define NNODES 32768   // 32*32*32

typedef __attribute__((ext_vector_type(8))) short bf16x8;   // 8 bf16 = 4 VGPRs
typedef __attribute__((ext_vector_type(4))) float f32x4;
typedef __attribute__((ext_vector_type(2))) float f32x2;

__device__ inline unsigned short f2bf(float f) {
    __hip_bfloat16 h = __float2bfloat16(f);
    return __builtin_bit_cast(unsigned short, h);
}

// ---------------------------------------------------------------------------
// x (b,c,m) fp32 -> xT2[bg][m][b2][c] bf16  (bg = b>>1, b2 = b&1).
// One node's pair-block = 128 B contiguous = 1 full cache line. (R4, verified)
// ---------------------------------------------------------------------------
__global__ __launch_bounds__(256) void build_xt_pair(
    const float* __restrict__ x, unsigned short* __restrict__ xT2) {
    __shared__ float tile[2][C_IN][65];
    const int bg    = blockIdx.y;             // 0..7 batch pair
    const int mbase = blockIdx.x * 64;
    const int tid   = threadIdx.x;

    #pragma unroll
    for (int i = 0; i < 4; ++i) {
        int lin = tid + i * 256;
        int mg  = lin & 15;
        int c   = (lin >> 4) & 31;
        int b2  = lin >> 9;
        float4 v = *reinterpret_cast<const float4*>(
            &x[((size_t)(bg * 2 + b2) * C_IN + c) * NNODES + mbase + mg * 4]);
        tile[b2][c][mg * 4 + 0] = v.x;
        tile[b2][c][mg * 4 + 1] = v.y;
        tile[b2][c][mg * 4 + 2] = v.z;
        tile[b2][c][mg * 4 + 3] = v.w;
    }
    __syncthreads();
    #pragma unroll
    for (int i = 0; i < 4; ++i) {
        int lin = tid + i * 256;
        int cg  = lin & 7;
        int b2  = (lin >> 3) & 1;
        int m0  = lin >> 4;
        ushort4 u;
        u.x = f2bf(tile[b2][cg * 4 + 0][m0]);
        u.y = f2bf(tile[b2][cg * 4 + 1][m0]);
        u.z = f2bf(tile[b2][cg * 4 + 2][m0]);
        u.w = f2bf(tile[b2][cg * 4 + 3][m0]);
        *reinterpret_cast<ushort4*>(
            &xT2[(((size_t)bg * NNODES + mbase + m0) << 6) + b2 * 32 + cg * 4]) = u;
    }
}

// ---------------------------------------------------------------------------
// W (o,c,r) fp32 -> Wp bf16 in MFMA A-frag order (unchanged, verified):
//   Wp[(((h*16 + r)*4 + g)*16 + row)*8 + e] = W[o=h*16+row][c=g*8+e][r]
// ---------------------------------------------------------------------------
__global__ __launch_bounds__(256) void build_w_bf16(
    const float* __restrict__ w, unsigned short* __restrict__ Wp) {
    int i = blockIdx.x * 256 + threadIdx.x;   // 16384
    int e   = i & 7;
    int row = (i >> 3) & 15;
    int g   = (i >> 7) & 3;
    int r   = (i >> 9) & 15;
    int h   = i >> 13;
    int o = h * 16 + row;
    int c = g * 8 + e;
    Wp[i] = f2bf(w[((size_t)o * C_IN + c) * NRAND + r]);
}

// ---------------------------------------------------------------------------
// Main MFMA kernel. GEMM cols = (nsub, b2): full-line 128 B gathers (8/instr).
// Tile PARITY interleave: a tile-pair covers n in [N0, N0+16); tile t owns
// n = N0 + 2*nsub + t. After both tiles each lane holds 2 consecutive-n
// values per (b,o) -> float2 NT stores = 64 B full-sector segments (R1-grade).
// ---------------------------------------------------------------------------
__global__ __launch_bounds__(256) void mixer_mfma(
    const unsigned short* __restrict__ xT2,
    const unsigned short* __restrict__ Wp,
    const float* __restrict__ bias,
    const int*   __restrict__ idx,
    float*       __restrict__ out) {
    __shared__ unsigned short wlds[2 * NRAND * 4 * 16 * 8];   // 32 KiB

    const int bid   = blockIdx.x;             // 0..2047
    const int bg    = bid & 7;                // batch pair == XCD (round-robin)
    const int chunk = bid >> 3;               // 0..255 (128-node chunks)

    const int lane  = threadIdx.x & 63;
    const int wave  = threadIdx.x >> 6;
    const int col   = lane & 15;
    const int b2    = col & 1;
    const int nsub  = col >> 1;               // 0..7
    const int g     = lane >> 4;              // k-chunk: c = g*8..g*8+7
    const int nbw   = chunk * 128 + wave * 32;  // wave covers 32 n

    const unsigned short* xg = xT2 + (((size_t)bg * NNODES) << 6);
    const int loff = b2 * 32 + g * 8;         // ushort offset in 128 B block

    // ---- W -> LDS fill (overlapped with first idx/gather issue) ----
    const int4* ibase = reinterpret_cast<const int4*>(idx);
    // pair p=0, tile t=0 rows: n = nbw + 2*nsub
    int4 ipE0, ipE1, ipE2, ipE3;
    {
        const int4* ip = ibase + (size_t)(nbw + 2 * nsub) * 4;
        ipE0 = ip[0]; ipE1 = ip[1]; ipE2 = ip[2]; ipE3 = ip[3];
    }
    {
        const uint4* src = reinterpret_cast<const uint4*>(Wp);
        uint4*       dst = reinterpret_cast<uint4*>(wlds);
        #pragma unroll
        for (int i = 0; i < 8; ++i)
            dst[threadIdx.x + i * 256] = src[threadIdx.x + i * 256];
    }

    #define GATHER4(d0, d1, d2, d3, iv)                                             \
        d0 = *reinterpret_cast<const bf16x8*>(xg + (((size_t)(iv).x) << 6) + loff); \
        d1 = *reinterpret_cast<const bf16x8*>(xg + (((size_t)(iv).y) << 6) + loff); \
        d2 = *reinterpret_cast<const bf16x8*>(xg + (((size_t)(iv).z) << 6) + loff); \
        d3 = *reinterpret_cast<const bf16x8*>(xg + (((size_t)(iv).w) << 6) + loff)

    #define MFMA8(cc0, cc1, buf, rbase)                                             \
        _Pragma("unroll")                                                           \
        for (int r = 0; r < 8; ++r) {                                               \
            cc0 = __builtin_amdgcn_mfma_f32_16x16x32_bf16(                          \
                      wfrag[((rbase + r) * 4 + g) * 16 + col], (buf)[r], cc0, 0,0,0);\
            cc1 = __builtin_amdgcn_mfma_f32_16x16x32_bf16(                          \
                      wfrag[((NRAND + rbase + r) * 4 + g) * 16 + col], (buf)[r], cc1, 0,0,0);\
        }

    bf16x8 bufA[8], bufB[8];
    GATHER4(bufA[0], bufA[1], bufA[2], bufA[3], ipE0);
    GATHER4(bufA[4], bufA[5], bufA[6], bufA[7], ipE1);

    __syncthreads();

    const bf16x8* wfrag = reinterpret_cast<const bf16x8*>(wlds);
    const float4  bv0   = reinterpret_cast<const float4*>(bias)[g];
    const float4  bv1   = reinterpret_cast<const float4*>(bias)[g + 4];

    #pragma unroll 1
    for (int p = 0; p < 2; ++p) {
        const int N0 = nbw + p * 16;

        // ---- tile t=0 (even parity) ----
        GATHER4(bufB[0], bufB[1], bufB[2], bufB[3], ipE2);
        GATHER4(bufB[4], bufB[5], bufB[6], bufB[7], ipE3);

        // idx rows for t=1 (odd parity), loaded under t0's MFMAs
        int4 ipO0, ipO1, ipO2, ipO3;
        {
            const int4* ip = ibase + (size_t)(N0 + 2 * nsub + 1) * 4;
            ipO0 = ip[0]; ipO1 = ip[1]; ipO2 = ip[2]; ipO3 = ip[3];
        }

        f32x4 d0c0 = {bv0.x, bv0.y, bv0.z, bv0.w};
        f32x4 d0c1 = {bv1.x, bv1.y, bv1.z, bv1.w};
        MFMA8(d0c0, d0c1, bufA, 0);

        // t1's first gather half under t0's second MFMA half
        GATHER4(bufA[0], bufA[1], bufA[2], bufA[3], ipO0);
        GATHER4(bufA[4], bufA[5], bufA[6], bufA[7], ipO1);

        MFMA8(d0c0, d0c1, bufB, 8);

        // ---- tile t=1 (odd parity) ----
        GATHER4(bufB[0], bufB[1], bufB[2], bufB[3], ipO2);
        GATHER4(bufB[4], bufB[5], bufB[6], bufB[7], ipO3);

        // prefetch next pair's even idx rows
        if (p == 0) {
            const int4* ip = ibase + (size_t)(nbw + 16 + 2 * nsub) * 4;
            ipE0 = ip[0]; ipE1 = ip[1]; ipE2 = ip[2]; ipE3 = ip[3];
        }

        f32x4 d1c0 = {bv0.x, bv0.y, bv0.z, bv0.w};
        f32x4 d1c1 = {bv1.x, bv1.y, bv1.z, bv1.w};
        MFMA8(d1c0, d1c1, bufA, 0);

        // next pair's even gathers under t1's second MFMA half
        if (p == 0) {
            GATHER4(bufA[0], bufA[1], bufA[2], bufA[3], ipE0);
            GATHER4(bufA[4], bufA[5], bufA[6], bufA[7], ipE1);
        }

        MFMA8(d1c0, d1c1, bufB, 8);

        // ---- store pair: lane holds n = N0+2nsub (t0) and +1 (t1) ----
        // per instr: 2 b2 x 4 g -> 8 segments x 64 B (full sectors)
        float* ob = out + (((size_t)(bg * 2 + b2) * C_OUT) << 15) + N0 + 2 * nsub;
        #pragma unroll
        for (int jr = 0; jr < 4; ++jr) {
            f32x2 v0 = {d0c0[jr], d1c0[jr]};
            f32x2 v1 = {d0c1[jr], d1c1[jr]};
            __builtin_nontemporal_store(v0,
                reinterpret_cast<f32x2*>(ob + (((size_t)(g * 4 + jr)) << 15)));
            __builtin_nontemporal_store(v1,
                reinterpret_cast<f32x2*>(ob + (((size_t)(g * 4 + jr + 16)) << 15)));
        }
    }
    #undef GATHER4
    #undef MFMA8
}

// ---------------------------------------------------------------------------
// fp32 fallback (ws too small) — round-0 kernel, known-correct.
// ---------------------------------------------------------------------------
__global__ __launch_bounds__(256) void mixer_fallback(
    const float* __restrict__ xsrc, const float* __restrict__ wsrc,
    const float* __restrict__ bias, const int* __restrict__ idx,
    float* __restrict__ out) {
    const int b = blockIdx.y;
    const int n = blockIdx.x * 256 + threadIdx.x;
    float acc[C_OUT];
    #pragma unroll
    for (int o = 0; o < C_OUT; ++o) acc[o] = bias[o];
    #pragma unroll 1
    for (int r = 0; r < NRAND; ++r) {
        const int m = idx[(size_t)n * NRAND + r];
        #pragma unroll
        for (int c = 0; c < C_IN; ++c) {
            const float xs = xsrc[((size_t)b * C_IN + c) * NNODES + m];
            #pragma unroll
            for (int o = 0; o < C_OUT; ++o)
                acc[o] += wsrc[((size_t)o * C_IN + c) * NRAND + r] * xs;
        }
    }
    #pragma unroll
    for (int o = 0; o < C_OUT; ++o)
        out[((size_t)b * C_OUT + o) * NNODES + n] = acc[o];
}

// ---------------------------------------------------------------------------
extern "C" void kernel_launch(void* const* d_in, const int* in_sizes, int n_in,
                              void* d_out, int out_size, void* d_ws, size_t ws_size,
                              hipStream_t stream) {
    const float* x    = (const float*)d_in[0];
    const float* w    = (const float*)d_in[1];
    const float* bias = (const float*)d_in[2];
    const int*   idx  = (const int*)d_in[3];
    float*       out  = (float*)d_out;

    const size_t xT_bytes = (size_t)BT * NNODES * C_IN * sizeof(unsigned short); // 32 MiB
    const size_t wp_bytes = (size_t)2 * NRAND * 4 * 16 * 8 * sizeof(unsigned short);

    if (ws_size >= xT_bytes + wp_bytes) {
        unsigned short* xT2 = (unsigned short*)d_ws;
        unsigned short* Wp  = (unsigned short*)((char*)d_ws + xT_bytes);

        dim3 tg(NNODES / 64, BT / 2);
        build_xt_pair<<<tg, 256, 0, stream>>>(x, xT2);
        build_w_bf16<<<(2 * NRAND * 4 * 16 * 8) / 256, 256, 0, stream>>>(w, Wp);

        mixer_mfma<<<BT / 2 * (NNODES / 128), 256, 0, stream>>>(xT2, Wp, bias, idx, out);
    } else {
        dim3 g(NNODES / 256, BT);
        mixer_fallback<<<g, 256, 0, stream>>>(x, w, bias, idx, out);
    }
}